// Round 20
// baseline (378.725 us; speedup 1.0000x reference)
//
#include <hip/hip_runtime.h>
#include <cfloat>

#define B_SZ 16
#define CD   256
#define NP   4096
#define KC   1024
#define TPB  256
#define EPS  0.04f

typedef short v8s __attribute__((ext_vector_type(8)));
typedef float v4f __attribute__((ext_vector_type(4)));

// ---- ws layout (bytes) ----
#define OFF_ESQ  0u
#define OFF_CNT  4096u
#define OFF_CODE 8192u
#define OFF_LIST 270336u
#define OFF_RED  532480u
#define OFF_WT   532480u
#define OFF_WH   4726784u
#define OFF_WL   5251072u
#define OFF_XH   5775360u
#define OFF_XL   39329792u
#define WS_NEED  72884224u

__device__ __forceinline__ unsigned short bf16rn(float v) {
    unsigned int u = __float_as_uint(v);
    unsigned int r = (u + 0x7FFFu + ((u >> 16) & 1u)) >> 16;
    return (unsigned short)r;
}
__device__ __forceinline__ float bf16f(unsigned short h) {
    return __uint_as_float(((unsigned int)h) << 16);
}

// ================= exact e_sq (np pairwise, verified) =================
__global__ void vq_esq(const float* __restrict__ w, float* __restrict__ esq_g)
{
    int k = blockIdx.x * blockDim.x + threadIdx.x;
    if (k >= KC) return;
    const float* wr = w + (size_t)k * CD;
    float halves[2];
    #pragma unroll
    for (int h = 0; h < 2; ++h) {
        const float* a = wr + h * 128;
        float r0 = __fmul_rn(a[0], a[0]);
        float r1 = __fmul_rn(a[1], a[1]);
        float r2 = __fmul_rn(a[2], a[2]);
        float r3 = __fmul_rn(a[3], a[3]);
        float r4 = __fmul_rn(a[4], a[4]);
        float r5 = __fmul_rn(a[5], a[5]);
        float r6 = __fmul_rn(a[6], a[6]);
        float r7 = __fmul_rn(a[7], a[7]);
        for (int i = 8; i < 128; i += 8) {
            r0 = __fadd_rn(r0, __fmul_rn(a[i + 0], a[i + 0]));
            r1 = __fadd_rn(r1, __fmul_rn(a[i + 1], a[i + 1]));
            r2 = __fadd_rn(r2, __fmul_rn(a[i + 2], a[i + 2]));
            r3 = __fadd_rn(r3, __fmul_rn(a[i + 3], a[i + 3]));
            r4 = __fadd_rn(r4, __fmul_rn(a[i + 4], a[i + 4]));
            r5 = __fadd_rn(r5, __fmul_rn(a[i + 5], a[i + 5]));
            r6 = __fadd_rn(r6, __fmul_rn(a[i + 6], a[i + 6]));
            r7 = __fadd_rn(r7, __fmul_rn(a[i + 7], a[i + 7]));
        }
        halves[h] = __fadd_rn(__fadd_rn(__fadd_rn(r0, r1), __fadd_rn(r2, r3)),
                              __fadd_rn(__fadd_rn(r4, r5), __fadd_rn(r6, r7)));
    }
    esq_g[k] = __fadd_rn(halves[0], halves[1]);
}

// ================= w split to bf16 hi (wl kept for layout compat, unused) =====
__global__ void vq_wsplit(const float* __restrict__ w, unsigned short* __restrict__ wh,
                          unsigned short* __restrict__ wl, int* __restrict__ cnt)
{
    if (blockIdx.x == 0 && threadIdx.x == 0) *cnt = 0;
    int i4 = (blockIdx.x * TPB + threadIdx.x) * 4;
    float4 v = *(const float4*)(w + i4);
    ushort4 hv = {bf16rn(v.x), bf16rn(v.y), bf16rn(v.z), bf16rn(v.w)};
    *(ushort4*)(wh + i4) = hv;
    (void)wl;
}

// ================= x transpose + bf16 hi only =================
__global__ void __launch_bounds__(TPB, 2)
vq_xsplit(const float* __restrict__ x, unsigned short* __restrict__ xh,
          unsigned short* __restrict__ xl)
{
    __shared__ float xs[CD][64];
    const int tid = threadIdx.x;
    const int b   = blockIdx.x >> 6;
    const int p0  = (blockIdx.x & 63) << 6;
    const float* xb = x + (size_t)b * CD * NP;
    const int g0 = b * NP + p0;

    #pragma unroll
    for (int r = 0; r < 16; ++r) {
        int f  = tid + r * TPB;
        int c  = f >> 4;
        int pq = (f & 15) << 2;
        float4 v = *(const float4*)(xb + (size_t)c * NP + p0 + pq);
        *(float4*)&xs[c][pq] = v;
    }
    __syncthreads();

    const int row = tid >> 2;
    #pragma unroll
    for (int s = 0; s < 8; ++s) {
        int slot = (tid & 3) + s * 4;
        int cb = slot * 8;
        float v0 = xs[cb + 0][row], v1 = xs[cb + 1][row], v2 = xs[cb + 2][row], v3 = xs[cb + 3][row];
        float v4 = xs[cb + 4][row], v5 = xs[cb + 5][row], v6 = xs[cb + 6][row], v7 = xs[cb + 7][row];
        unsigned short h0 = bf16rn(v0), h1 = bf16rn(v1), h2 = bf16rn(v2), h3 = bf16rn(v3);
        unsigned short h4 = bf16rn(v4), h5 = bf16rn(v5), h6 = bf16rn(v6), h7 = bf16rn(v7);
        int4 vh;
        vh.x = (int)h0 | ((int)h1 << 16);
        vh.y = (int)h2 | ((int)h3 << 16);
        vh.z = (int)h4 | ((int)h5 << 16);
        vh.w = (int)h6 | ((int)h7 << 16);
        size_t o = (size_t)(g0 + row) * CD + cb;
        *(int4*)(xh + o) = vh;
    }
    (void)xl;
}

// ================= MFMA GEMM + per-tile best/2nd (K=256, 4 chunks) =======
// R20: launch bound REMOVED -> natural VGPR (~84) gives occupancy
// min(LDS 160/40=4, VGPR) = 4 blocks/CU -> grid 4096/1024 = exactly 4 rounds
// (was 3 blocks/CU -> 5.33 rounds, ~19% tail waste).
#define LEX_COMBINE(d1, i1, dv, od, oi, ov)                         \
    if ((od) < (d1) || ((od) == (d1) && (oi) < (i1))) {             \
        dv = fminf((d1), (ov)); d1 = (od); i1 = (oi);               \
    } else { dv = fminf((dv), (od)); }

#define VQ_LOAD(T, A0, A1, B0, B1, B2, B3, B4, B5, B6, B7)                    \
    {                                                                         \
        const int kcn_  = (T) < 3 ? (T) : 3;                                  \
        const int ke_   = kcn_ * 64;                                          \
        const unsigned short* sa_ = xh + (size_t)(g0 + rB) * CD + ke_ + sB * 8; \
        A0 = *(const int4*)(sa_);                                             \
        A1 = *(const int4*)(sa_ + 32 * CD);                                   \
        const unsigned short* sb_ = wh + (size_t)(n0 + rB) * CD + ke_ + sB * 8; \
        B0 = *(const int4*)(sb_ + 0 * 32 * CD);                               \
        B1 = *(const int4*)(sb_ + 1 * 32 * CD);                               \
        B2 = *(const int4*)(sb_ + 2 * 32 * CD);                               \
        B3 = *(const int4*)(sb_ + 3 * 32 * CD);                               \
        B4 = *(const int4*)(sb_ + 4 * 32 * CD);                               \
        B5 = *(const int4*)(sb_ + 5 * 32 * CD);                               \
        B6 = *(const int4*)(sb_ + 6 * 32 * CD);                               \
        B7 = *(const int4*)(sb_ + 7 * 32 * CD);                               \
    }

#define VQ_WRITE(A0, A1, B0, B1, B2, B3, B4, B5, B6, B7)                      \
    {                                                                         \
        unsigned short* aa_ = smem + rB * 64 + swz;                           \
        *(int4*)(aa_)            = A0;                                        \
        *(int4*)(aa_ + 32 * 64)  = A1;                                        \
        unsigned short* bb_ = smem + 4096 + rB * 64 + swz;                    \
        *(int4*)(bb_ + 0 * 2048) = B0; *(int4*)(bb_ + 1 * 2048) = B1;         \
        *(int4*)(bb_ + 2 * 2048) = B2; *(int4*)(bb_ + 3 * 2048) = B3;         \
        *(int4*)(bb_ + 4 * 2048) = B4; *(int4*)(bb_ + 5 * 2048) = B5;         \
        *(int4*)(bb_ + 6 * 2048) = B6; *(int4*)(bb_ + 7 * 2048) = B7;         \
    }

#define VQ_COMP()                                                                         \
    {                                                                                     \
        const unsigned short* Ab = smem;                                                  \
        const unsigned short* Bb = smem + 4096;                                           \
        for (int kk = 0; kk < 2; ++kk) {                                                  \
            const int s8 = ((hi2 + kk * 4) ^ rxor) * 8;                                   \
            v8s af0 = *(const v8s*)(Ab + (0 * 16 + lo4) * 64 + s8);                       \
            v8s af1 = *(const v8s*)(Ab + (1 * 16 + lo4) * 64 + s8);                       \
            v8s af2 = *(const v8s*)(Ab + (2 * 16 + lo4) * 64 + s8);                       \
            v8s af3 = *(const v8s*)(Ab + (3 * 16 + lo4) * 64 + s8);                       \
            v8s bf0 = *(const v8s*)(Bb + (wv * 64 + 0 * 16 + lo4) * 64 + s8);             \
            v8s bf1 = *(const v8s*)(Bb + (wv * 64 + 1 * 16 + lo4) * 64 + s8);             \
            v8s bf2 = *(const v8s*)(Bb + (wv * 64 + 2 * 16 + lo4) * 64 + s8);             \
            v8s bf3 = *(const v8s*)(Bb + (wv * 64 + 3 * 16 + lo4) * 64 + s8);             \
            acc[0][0] = __builtin_amdgcn_mfma_f32_16x16x32_bf16(af0, bf0, acc[0][0], 0, 0, 0); \
            acc[0][1] = __builtin_amdgcn_mfma_f32_16x16x32_bf16(af0, bf1, acc[0][1], 0, 0, 0); \
            acc[0][2] = __builtin_amdgcn_mfma_f32_16x16x32_bf16(af0, bf2, acc[0][2], 0, 0, 0); \
            acc[0][3] = __builtin_amdgcn_mfma_f32_16x16x32_bf16(af0, bf3, acc[0][3], 0, 0, 0); \
            acc[1][0] = __builtin_amdgcn_mfma_f32_16x16x32_bf16(af1, bf0, acc[1][0], 0, 0, 0); \
            acc[1][1] = __builtin_amdgcn_mfma_f32_16x16x32_bf16(af1, bf1, acc[1][1], 0, 0, 0); \
            acc[1][2] = __builtin_amdgcn_mfma_f32_16x16x32_bf16(af1, bf2, acc[1][2], 0, 0, 0); \
            acc[1][3] = __builtin_amdgcn_mfma_f32_16x16x32_bf16(af1, bf3, acc[1][3], 0, 0, 0); \
            acc[2][0] = __builtin_amdgcn_mfma_f32_16x16x32_bf16(af2, bf0, acc[2][0], 0, 0, 0); \
            acc[2][1] = __builtin_amdgcn_mfma_f32_16x16x32_bf16(af2, bf1, acc[2][1], 0, 0, 0); \
            acc[2][2] = __builtin_amdgcn_mfma_f32_16x16x32_bf16(af2, bf2, acc[2][2], 0, 0, 0); \
            acc[2][3] = __builtin_amdgcn_mfma_f32_16x16x32_bf16(af2, bf3, acc[2][3], 0, 0, 0); \
            acc[3][0] = __builtin_amdgcn_mfma_f32_16x16x32_bf16(af3, bf0, acc[3][0], 0, 0, 0); \
            acc[3][1] = __builtin_amdgcn_mfma_f32_16x16x32_bf16(af3, bf1, acc[3][1], 0, 0, 0); \
            acc[3][2] = __builtin_amdgcn_mfma_f32_16x16x32_bf16(af3, bf2, acc[3][2], 0, 0, 0); \
            acc[3][3] = __builtin_amdgcn_mfma_f32_16x16x32_bf16(af3, bf3, acc[3][3], 0, 0, 0); \
        }                                                                                 \
    }

__global__ void
vq_mfma(const unsigned short* __restrict__ xh, const unsigned short* __restrict__ xl,
        const unsigned short* __restrict__ wh, const unsigned short* __restrict__ wl,
        const float* __restrict__ esq, float4* __restrict__ redg)
{
    __shared__ unsigned short smem[20480];          // 40 KB: As 8KB | Bs 32KB

    const int tid = threadIdx.x;
    const int mt  = blockIdx.x >> 2;
    const int nt  = blockIdx.x & 3;
    const int g0  = mt * 64;
    const int n0  = nt * 256;

    const int wv  = tid >> 6;
    const int l   = tid & 63;
    const int lo4 = l & 15;
    const int hi2 = l >> 4;
    const int rxor = lo4 & 7;

    const int rB  = tid >> 3;
    const int sB  = tid & 7;
    const int swz = ((sB ^ (rB & 7)) * 8);

    v4f acc[4][4];
    #pragma unroll
    for (int i = 0; i < 4; ++i)
        #pragma unroll
        for (int j = 0; j < 4; ++j) acc[i][j] = (v4f)0.f;

    int4 pa0, pa1, pb0, pb1, pb2, pb3, pb4, pb5, pb6, pb7;

    VQ_LOAD(0, pa0, pa1, pb0, pb1, pb2, pb3, pb4, pb5, pb6, pb7)
    VQ_WRITE(pa0, pa1, pb0, pb1, pb2, pb3, pb4, pb5, pb6, pb7)
    VQ_LOAD(1, pa0, pa1, pb0, pb1, pb2, pb3, pb4, pb5, pb6, pb7)
    __syncthreads();

    for (int kc = 0; kc < 4; ++kc) {                // K = 256: 4 chunks
        VQ_COMP()
        __syncthreads();
        VQ_WRITE(pa0, pa1, pb0, pb1, pb2, pb3, pb4, pb5, pb6, pb7)
        VQ_LOAD(kc + 2, pa0, pa1, pb0, pb1, pb2, pb3, pb4, pb5, pb6, pb7)
        __syncthreads();
    }

    const float eq0 = esq[n0 + wv * 64 + 0 * 16 + lo4];
    const float eq1 = esq[n0 + wv * 64 + 1 * 16 + lo4];
    const float eq2 = esq[n0 + wv * 64 + 2 * 16 + lo4];
    const float eq3 = esq[n0 + wv * 64 + 3 * 16 + lo4];
    const int nbase = n0 + wv * 64;

    float4* red4 = (float4*)smem;

    #pragma unroll
    for (int i = 0; i < 4; ++i) {
        float d1[4], dv[4]; int ix[4];
        #pragma unroll
        for (int r = 0; r < 4; ++r) {
            float s = fmaf(-2.f, acc[i][0][r], eq0);
            d1[r] = s; ix[r] = nbase + lo4; dv[r] = FLT_MAX;
        }
        #pragma unroll
        for (int r = 0; r < 4; ++r) {
            float s1 = fmaf(-2.f, acc[i][1][r], eq1);
            if (s1 < d1[r]) { dv[r] = d1[r]; d1[r] = s1; ix[r] = nbase + 16 + lo4; }
            else dv[r] = fminf(dv[r], s1);
            float s2 = fmaf(-2.f, acc[i][2][r], eq2);
            if (s2 < d1[r]) { dv[r] = d1[r]; d1[r] = s2; ix[r] = nbase + 32 + lo4; }
            else dv[r] = fminf(dv[r], s2);
            float s3 = fmaf(-2.f, acc[i][3][r], eq3);
            if (s3 < d1[r]) { dv[r] = d1[r]; d1[r] = s3; ix[r] = nbase + 48 + lo4; }
            else dv[r] = fminf(dv[r], s3);
        }
        #pragma unroll
        for (int m = 1; m <= 8; m <<= 1) {
            #pragma unroll
            for (int r = 0; r < 4; ++r) {
                float od = __shfl_xor(d1[r], m);
                int   oi = __shfl_xor(ix[r], m);
                float ov = __shfl_xor(dv[r], m);
                LEX_COMBINE(d1[r], ix[r], dv[r], od, oi, ov)
            }
        }
        if (lo4 == 0) {
            #pragma unroll
            for (int r = 0; r < 4; ++r) {
                float4 e; e.x = d1[r]; e.y = dv[r]; e.z = __int_as_float(ix[r]); e.w = 0.f;
                red4[wv * 64 + i * 16 + hi2 * 4 + r] = e;
            }
        }
    }
    __syncthreads();

    if (tid < 64) {
        float4 a = red4[tid];
        #pragma unroll
        for (int w2 = 1; w2 < 4; ++w2) {
            float4 c = red4[w2 * 64 + tid];
            float od = c.x; int oi = __float_as_int(c.z); float ov = c.y;
            float d1 = a.x; int i1 = __float_as_int(a.z); float dv = a.y;
            LEX_COMBINE(d1, i1, dv, od, oi, ov)
            a.x = d1; a.y = dv; a.z = __int_as_float(i1);
        }
        redg[(size_t)(g0 + tid) * 4 + nt] = a;
    }
}

// ================= combine 4 n-tiles, write codes, flag near-ties =================
__global__ void vq_finalize(const float4* __restrict__ redg, float* __restrict__ out,
                            int* __restrict__ codes, int* __restrict__ cnt,
                            int* __restrict__ list)
{
    int g = blockIdx.x * TPB + threadIdx.x;
    float4 a = redg[(size_t)g * 4 + 0];
    float d1 = a.x; int i1 = __float_as_int(a.z); float dv = a.y;
    #pragma unroll
    for (int t = 1; t < 4; ++t) {
        float4 c = redg[(size_t)g * 4 + t];
        float od = c.x; int oi = __float_as_int(c.z); float ov = c.y;
        LEX_COMBINE(d1, i1, dv, od, oi, ov)
    }
    out[g] = (float)i1;
    codes[g] = i1;
    if (dv - d1 < EPS) {
        int pos = atomicAdd(cnt, 1);
        list[pos] = g;
    }
}

// ================= w transpose (fp32) for coalesced rescore =================
__global__ void vq_wT(const float* __restrict__ w, float* __restrict__ wT)
{
    __shared__ float tile[32][33];
    const int tid = threadIdx.x;
    const int r0 = blockIdx.x * 32;
    const int cc = tid & 31;
    const int rr0 = (tid >> 5) * 4;
    for (int ct = 0; ct < 8; ++ct) {
        __syncthreads();
        #pragma unroll
        for (int k = 0; k < 4; ++k)
            tile[rr0 + k][cc] = w[(size_t)(r0 + rr0 + k) * CD + ct * 32 + cc];
        __syncthreads();
        #pragma unroll
        for (int k = 0; k < 4; ++k)
            wT[(size_t)(ct * 32 + rr0 + k) * KC + r0 + cc] = tile[cc][rr0 + k];
    }
}

// ================= exact rescore, coalesced + amortized (8 points/block) =================
#define RACC(pp) float a##pp##0 = 0.f, a##pp##1 = 0.f, a##pp##2 = 0.f, a##pp##3 = 0.f;
#define RFMA(pp)                                          \
    {                                                     \
        float xv = xrow[pp][c];                           \
        a##pp##0 = fmaf(xv, w0v, a##pp##0);               \
        a##pp##1 = fmaf(xv, w1v, a##pp##1);               \
        a##pp##2 = fmaf(xv, w2v, a##pp##2);               \
        a##pp##3 = fmaf(xv, w3v, a##pp##3);               \
    }
#define REPI(pp)                                                                     \
    if (pp < m) {                                                                    \
        float xq = xqs[pp];                                                          \
        float bd; int bi;                                                            \
        float d2 = __fadd_rn(__fsub_rn(xq, __fmul_rn(2.0f, a##pp##0)), e0);          \
        bd = d2; bi = tid;                                                           \
        d2 = __fadd_rn(__fsub_rn(xq, __fmul_rn(2.0f, a##pp##1)), e1);                \
        if (d2 < bd) { bd = d2; bi = tid + 256; }                                    \
        d2 = __fadd_rn(__fsub_rn(xq, __fmul_rn(2.0f, a##pp##2)), e2);                \
        if (d2 < bd) { bd = d2; bi = tid + 512; }                                    \
        d2 = __fadd_rn(__fsub_rn(xq, __fmul_rn(2.0f, a##pp##3)), e3);                \
        if (d2 < bd) { bd = d2; bi = tid + 768; }                                    \
        sd[pp][tid] = bd; si[pp][tid] = bi;                                          \
    }

__global__ void vq_rescore(const float* __restrict__ x, const float* __restrict__ wT,
                           const float* __restrict__ esq, const int* __restrict__ cnt,
                           const int* __restrict__ list, float* __restrict__ out,
                           int* __restrict__ codes)
{
    __shared__ float xrow[8][CD];
    __shared__ float xqs[8];
    __shared__ float sd[8][TPB];
    __shared__ int   si[8][TPB];
    const int tid = threadIdx.x;
    const int n = *cnt;

    for (int base = blockIdx.x * 8; base < n; base += gridDim.x * 8) {
        const int m = (n - base < 8) ? (n - base) : 8;
        __syncthreads();
        #pragma unroll
        for (int pp = 0; pp < 8; ++pp) {
            if (pp < m) {
                const int g = list[base + pp];
                const int b = g >> 12, p = g & 4095;
                xrow[pp][tid] = x[(size_t)b * CD * NP + (size_t)tid * NP + p];
            } else {
                xrow[pp][tid] = 0.f;
            }
        }
        __syncthreads();
        if (tid < m) {
            const int pp = tid;
            float halves[2];
            #pragma unroll
            for (int h = 0; h < 2; ++h) {
                const float* a = &xrow[pp][h * 128];
                float r0 = __fmul_rn(a[0], a[0]);
                float r1 = __fmul_rn(a[1], a[1]);
                float r2 = __fmul_rn(a[2], a[2]);
                float r3 = __fmul_rn(a[3], a[3]);
                float r4 = __fmul_rn(a[4], a[4]);
                float r5 = __fmul_rn(a[5], a[5]);
                float r6 = __fmul_rn(a[6], a[6]);
                float r7 = __fmul_rn(a[7], a[7]);
                for (int i = 8; i < 128; i += 8) {
                    r0 = __fadd_rn(r0, __fmul_rn(a[i + 0], a[i + 0]));
                    r1 = __fadd_rn(r1, __fmul_rn(a[i + 1], a[i + 1]));
                    r2 = __fadd_rn(r2, __fmul_rn(a[i + 2], a[i + 2]));
                    r3 = __fadd_rn(r3, __fmul_rn(a[i + 3], a[i + 3]));
                    r4 = __fadd_rn(r4, __fmul_rn(a[i + 4], a[i + 4]));
                    r5 = __fadd_rn(r5, __fmul_rn(a[i + 5], a[i + 5]));
                    r6 = __fadd_rn(r6, __fmul_rn(a[i + 6], a[i + 6]));
                    r7 = __fadd_rn(r7, __fmul_rn(a[i + 7], a[i + 7]));
                }
                halves[h] = __fadd_rn(__fadd_rn(__fadd_rn(r0, r1), __fadd_rn(r2, r3)),
                                      __fadd_rn(__fadd_rn(r4, r5), __fadd_rn(r6, r7)));
            }
            xqs[pp] = __fadd_rn(halves[0], halves[1]);
        }
        __syncthreads();

        RACC(0) RACC(1) RACC(2) RACC(3) RACC(4) RACC(5) RACC(6) RACC(7)
        #pragma unroll 4
        for (int c = 0; c < CD; ++c) {
            const float* wTc = wT + ((size_t)c << 10);
            float w0v = wTc[tid];
            float w1v = wTc[tid + 256];
            float w2v = wTc[tid + 512];
            float w3v = wTc[tid + 768];
            RFMA(0) RFMA(1) RFMA(2) RFMA(3) RFMA(4) RFMA(5) RFMA(6) RFMA(7)
        }

        const float e0 = esq[tid];
        const float e1 = esq[tid + 256];
        const float e2 = esq[tid + 512];
        const float e3 = esq[tid + 768];
        REPI(0) REPI(1) REPI(2) REPI(3) REPI(4) REPI(5) REPI(6) REPI(7)
        __syncthreads();

        if (tid < m) {
            const int pp = tid;
            float d1 = sd[pp][0]; int i1 = si[pp][0];
            for (int t = 1; t < TPB; ++t) {
                float od = sd[pp][t]; int oi = si[pp][t];
                if (od < d1 || (od == d1 && oi < i1)) { d1 = od; i1 = oi; }
            }
            const int g = list[base + pp];
            codes[g] = i1;
            out[g] = (float)i1;
        }
    }
}

// ================= gather x_new (LDS-staged, coalesced w reads) =================
__global__ void __launch_bounds__(TPB, 2)
vq_gather(const float* __restrict__ w, const int* __restrict__ codes,
          float* __restrict__ outx)
{
    __shared__ float lw[64][257];
    __shared__ int   lc[64];
    const int tid = threadIdx.x;
    const int b   = blockIdx.x >> 6;
    const int p0  = (blockIdx.x & 63) << 6;

    if (tid < 64) lc[tid] = codes[b * NP + p0 + tid];
    __syncthreads();

    #pragma unroll 8
    for (int pp = 0; pp < 64; ++pp) {
        lw[pp][tid] = w[(size_t)lc[pp] * CD + tid];
    }
    __syncthreads();

    const int p  = tid & 63;
    const int cg = tid >> 6;
    size_t obase = (size_t)b * CD * NP + (size_t)p0 + p;
    #pragma unroll 8
    for (int r = 0; r < 64; ++r) {
        int c = (cg << 6) + r;
        outx[obase + (size_t)c * NP] = lw[p][c];
    }
}

// ================= R3 fallback (proven exact fp32 path, needs only 4 KB ws) =================
#define FMA_ROW(i, xc)                              \
    acc##i##0 = fmaf((xc), wv0.x, acc##i##0);       \
    acc##i##1 = fmaf((xc), wv0.y, acc##i##1);       \
    acc##i##2 = fmaf((xc), wv0.z, acc##i##2);       \
    acc##i##3 = fmaf((xc), wv0.w, acc##i##3);       \
    acc##i##4 = fmaf((xc), wv1.x, acc##i##4);       \
    acc##i##5 = fmaf((xc), wv1.y, acc##i##5);       \
    acc##i##6 = fmaf((xc), wv1.z, acc##i##6);       \
    acc##i##7 = fmaf((xc), wv1.w, acc##i##7);
#define D2_ONE(i, j, ev)                                                          \
    {                                                                             \
        float d2 = __fadd_rn(__fsub_rn(xq[i], __fmul_rn(2.0f, acc##i##j)), (ev)); \
        if (d2 < bestd[i]) { bestd[i] = d2; besti[i] = fn0 + jl + j; }            \
    }
#define D2_ROW(i)                                                                 \
    D2_ONE(i, 0, e0.x) D2_ONE(i, 1, e0.y) D2_ONE(i, 2, e0.z) D2_ONE(i, 3, e0.w)  \
    D2_ONE(i, 4, e1.x) D2_ONE(i, 5, e1.y) D2_ONE(i, 6, e1.z) D2_ONE(i, 7, e1.w)
#define DECL_ACC(i) \
    float acc##i##0 = 0.f, acc##i##1 = 0.f, acc##i##2 = 0.f, acc##i##3 = 0.f, \
          acc##i##4 = 0.f, acc##i##5 = 0.f, acc##i##6 = 0.f, acc##i##7 = 0.f;

__global__ void __launch_bounds__(TPB, 2)
vq_fused(const float* __restrict__ x, const float* __restrict__ w,
         const float* __restrict__ esq_g, float* __restrict__ out)
{
    __shared__ float xs[CD][64];
    __shared__ float ws[2][16][128];
    const int tid = threadIdx.x;
    const int blk = blockIdx.x;
    const int b   = blk >> 6;
    const int p0  = (blk & 63) << 6;
    const float* xb = x + (size_t)b * CD * NP;
    #pragma unroll
    for (int r = 0; r < 16; ++r) {
        int f  = tid + r * TPB;
        int c  = f >> 4;
        int pq = (f & 15) << 2;
        float4 v = *(const float4*)(xb + (size_t)c * NP + p0 + pq);
        *(float4*)&xs[c][pq] = v;
    }
    __syncthreads();
    const int sj = tid & 63;
    const int sc = (tid >> 6) << 2;
    const float* wbase = w + (size_t)sj * CD + sc;
    float* xsq_tmp = &ws[1][0][0];
    if (tid < 64) {
        float halves[2];
        #pragma unroll
        for (int h = 0; h < 2; ++h) {
            int cb = h * 128;
            float r0 = __fmul_rn(xs[cb + 0][tid], xs[cb + 0][tid]);
            float r1 = __fmul_rn(xs[cb + 1][tid], xs[cb + 1][tid]);
            float r2 = __fmul_rn(xs[cb + 2][tid], xs[cb + 2][tid]);
            float r3 = __fmul_rn(xs[cb + 3][tid], xs[cb + 3][tid]);
            float r4 = __fmul_rn(xs[cb + 4][tid], xs[cb + 4][tid]);
            float r5 = __fmul_rn(xs[cb + 5][tid], xs[cb + 5][tid]);
            float r6 = __fmul_rn(xs[cb + 6][tid], xs[cb + 6][tid]);
            float r7 = __fmul_rn(xs[cb + 7][tid], xs[cb + 7][tid]);
            for (int i = 8; i < 128; i += 8) {
                r0 = __fadd_rn(r0, __fmul_rn(xs[cb + i + 0][tid], xs[cb + i + 0][tid]));
                r1 = __fadd_rn(r1, __fmul_rn(xs[cb + i + 1][tid], xs[cb + i + 1][tid]));
                r2 = __fadd_rn(r2, __fmul_rn(xs[cb + i + 2][tid], xs[cb + i + 2][tid]));
                r3 = __fadd_rn(r3, __fmul_rn(xs[cb + i + 3][tid], xs[cb + i + 3][tid]));
                r4 = __fadd_rn(r4, __fmul_rn(xs[cb + i + 4][tid], xs[cb + i + 4][tid]));
                r5 = __fadd_rn(r5, __fmul_rn(xs[cb + i + 5][tid], xs[cb + i + 5][tid]));
                r6 = __fadd_rn(r6, __fmul_rn(xs[cb + i + 6][tid], xs[cb + i + 6][tid]));
                r7 = __fadd_rn(r7, __fmul_rn(xs[cb + i + 7][tid], xs[cb + i + 7][tid]));
            }
            halves[h] = __fadd_rn(__fadd_rn(__fadd_rn(r0, r1), __fadd_rn(r2, r3)),
                                  __fadd_rn(__fadd_rn(r4, r5), __fadd_rn(r6, r7)));
        }
        xsq_tmp[tid] = __fadd_rn(halves[0], halves[1]);
    }
    {
        #pragma unroll
        for (int r = 0; r < 2; ++r) {
            int j = sj + (r << 6);
            float4 v = *(const float4*)(w + (size_t)j * CD + sc);
            ws[0][sc + 0][j] = v.x; ws[0][sc + 1][j] = v.y;
            ws[0][sc + 2][j] = v.z; ws[0][sc + 3][j] = v.w;
        }
    }
    __syncthreads();
    const int pl = (tid & 15) << 2;
    const int jl = (tid >> 4) << 3;
    float xq[4] = { xsq_tmp[pl], xsq_tmp[pl + 1], xsq_tmp[pl + 2], xsq_tmp[pl + 3] };
    __syncthreads();
    float bestd[4] = {FLT_MAX, FLT_MAX, FLT_MAX, FLT_MAX};
    int   besti[4] = {0, 0, 0, 0};
    for (int tile = 0; tile < 8; ++tile) {
        const int fn0 = tile * 128;
        float4 e0 = *(const float4*)(esq_g + fn0 + jl);
        float4 e1 = *(const float4*)(esq_g + fn0 + jl + 4);
        DECL_ACC(0) DECL_ACC(1) DECL_ACC(2) DECL_ACC(3)
        for (int ch = 0; ch < 16; ++ch) {
            const int t   = tile * 16 + ch;
            const int cur = t & 1;
            const int tn  = (t + 1) & 127;
            const size_t poff = (size_t)((tn >> 4) << 7) * CD + ((tn & 15) << 4);
            float4 pa = *(const float4*)(wbase + poff);
            float4 pb = *(const float4*)(wbase + poff + (size_t)64 * CD);
            const int c0 = ch * 16;
            #pragma unroll
            for (int c = 0; c < 16; ++c) {
                float4 xv  = *(const float4*)&xs[c0 + c][pl];
                float4 wv0 = *(const float4*)&ws[cur][c][jl];
                float4 wv1 = *(const float4*)&ws[cur][c][jl + 4];
                FMA_ROW(0, xv.x)
                FMA_ROW(1, xv.y)
                FMA_ROW(2, xv.z)
                FMA_ROW(3, xv.w)
            }
            {
                const int nb = cur ^ 1;
                ws[nb][sc + 0][sj]      = pa.x; ws[nb][sc + 1][sj]      = pa.y;
                ws[nb][sc + 2][sj]      = pa.z; ws[nb][sc + 3][sj]      = pa.w;
                ws[nb][sc + 0][sj + 64] = pb.x; ws[nb][sc + 1][sj + 64] = pb.y;
                ws[nb][sc + 2][sj + 64] = pb.z; ws[nb][sc + 3][sj + 64] = pb.w;
            }
            __syncthreads();
        }
        D2_ROW(0) D2_ROW(1) D2_ROW(2) D2_ROW(3)
    }
    __syncthreads();
    float* redd  = &ws[0][0][0];
    int*   redi  = (int*)(redd + 1024);
    int*   codes = (int*)&ws[1][0][0];
    {
        int g = tid >> 4;
        #pragma unroll
        for (int i = 0; i < 4; ++i) {
            redd[(pl + i) * 16 + g] = bestd[i];
            redi[(pl + i) * 16 + g] = besti[i];
        }
    }
    __syncthreads();
    if (tid < 64) {
        float bd = FLT_MAX; int bi = 0x7fffffff;
        #pragma unroll
        for (int g = 0; g < 16; ++g) {
            float d = redd[tid * 16 + g];
            int   i = redi[tid * 16 + g];
            if (d < bd || (d == bd && i < bi)) { bd = d; bi = i; }
        }
        codes[tid] = bi;
        out[(size_t)b * NP + p0 + tid] = (float)bi;
    }
    __syncthreads();
    {
        float* outx = out + (size_t)B_SZ * NP;
        int p  = tid & 63;
        int cg = tid >> 6;
        const float* wr = w + (size_t)codes[p] * CD;
        size_t obase = (size_t)b * CD * NP + (size_t)p0 + p;
        #pragma unroll 4
        for (int r = 0; r < 64; ++r) {
            int c = (cg << 6) + r;
            outx[obase + (size_t)c * NP] = wr[c];
        }
    }
}

extern "C" void kernel_launch(void* const* d_in, const int* in_sizes, int n_in,
                              void* d_out, int out_size, void* d_ws, size_t ws_size,
                              hipStream_t stream)
{
    const float* x = (const float*)d_in[0];     // [16,256,64,64]
    const float* w = (const float*)d_in[1];     // [1024,256]
    float* out    = (float*)d_out;              // 65536 code + 16777216 x_new
    char*  ws     = (char*)d_ws;

    float* esq = (float*)(ws + OFF_ESQ);
    hipLaunchKernelGGL(vq_esq, dim3(4), dim3(TPB), 0, stream, w, esq);

    if (ws_size < (size_t)WS_NEED) {
        hipLaunchKernelGGL(vq_fused, dim3(1024), dim3(TPB), 0, stream, x, w, esq, out);
        return;
    }

    int*   cnt   = (int*)(ws + OFF_CNT);
    int*   codes = (int*)(ws + OFF_CODE);
    int*   list  = (int*)(ws + OFF_LIST);
    float4* redg = (float4*)(ws + OFF_RED);
    float*  wT   = (float*)(ws + OFF_WT);
    unsigned short* wh = (unsigned short*)(ws + OFF_WH);
    unsigned short* wl = (unsigned short*)(ws + OFF_WL);
    unsigned short* xh = (unsigned short*)(ws + OFF_XH);
    unsigned short* xl = (unsigned short*)(ws + OFF_XL);

    hipLaunchKernelGGL(vq_wsplit,   dim3(256),  dim3(TPB), 0, stream, w, wh, wl, cnt);
    hipLaunchKernelGGL(vq_xsplit,   dim3(1024), dim3(TPB), 0, stream, x, xh, xl);
    hipLaunchKernelGGL(vq_mfma,     dim3(4096), dim3(TPB), 0, stream, xh, xl, wh, wl, esq, redg);
    hipLaunchKernelGGL(vq_finalize, dim3(256),  dim3(TPB), 0, stream, redg, out, codes, cnt, list);
    hipLaunchKernelGGL(vq_wT,       dim3(32),   dim3(TPB), 0, stream, w, wT);
    hipLaunchKernelGGL(vq_rescore,  dim3(1024), dim3(TPB), 0, stream, x, wT, esq, cnt, list, out, codes);
    hipLaunchKernelGGL(vq_gather,   dim3(1024), dim3(TPB), 0, stream, w, codes, out + (size_t)B_SZ * NP);
}

// Round 21
// 230.246 us; speedup vs baseline: 1.6449x; 1.6449x over previous
//
#include <hip/hip_runtime.h>
#include <cfloat>

#define B_SZ 16
#define CD   256
#define NP   4096
#define KC   1024
#define TPB  256
#define EPS  0.04f

typedef short v8s __attribute__((ext_vector_type(8)));
typedef float v4f __attribute__((ext_vector_type(4)));

// ---- ws layout (bytes) ----
#define OFF_ESQ  0u
#define OFF_CNT  4096u
#define OFF_CODE 8192u
#define OFF_LIST 270336u
#define OFF_RED  532480u
#define OFF_WT   532480u
#define OFF_WH   4726784u
#define OFF_WL   5251072u
#define OFF_XH   5775360u
#define OFF_XL   39329792u
#define WS_NEED  72884224u

__device__ __forceinline__ unsigned short bf16rn(float v) {
    unsigned int u = __float_as_uint(v);
    unsigned int r = (u + 0x7FFFu + ((u >> 16) & 1u)) >> 16;
    return (unsigned short)r;
}
__device__ __forceinline__ float bf16f(unsigned short h) {
    return __uint_as_float(((unsigned int)h) << 16);
}

// ================= exact e_sq (np pairwise, verified) =================
__global__ void vq_esq(const float* __restrict__ w, float* __restrict__ esq_g)
{
    int k = blockIdx.x * blockDim.x + threadIdx.x;
    if (k >= KC) return;
    const float* wr = w + (size_t)k * CD;
    float halves[2];
    #pragma unroll
    for (int h = 0; h < 2; ++h) {
        const float* a = wr + h * 128;
        float r0 = __fmul_rn(a[0], a[0]);
        float r1 = __fmul_rn(a[1], a[1]);
        float r2 = __fmul_rn(a[2], a[2]);
        float r3 = __fmul_rn(a[3], a[3]);
        float r4 = __fmul_rn(a[4], a[4]);
        float r5 = __fmul_rn(a[5], a[5]);
        float r6 = __fmul_rn(a[6], a[6]);
        float r7 = __fmul_rn(a[7], a[7]);
        for (int i = 8; i < 128; i += 8) {
            r0 = __fadd_rn(r0, __fmul_rn(a[i + 0], a[i + 0]));
            r1 = __fadd_rn(r1, __fmul_rn(a[i + 1], a[i + 1]));
            r2 = __fadd_rn(r2, __fmul_rn(a[i + 2], a[i + 2]));
            r3 = __fadd_rn(r3, __fmul_rn(a[i + 3], a[i + 3]));
            r4 = __fadd_rn(r4, __fmul_rn(a[i + 4], a[i + 4]));
            r5 = __fadd_rn(r5, __fmul_rn(a[i + 5], a[i + 5]));
            r6 = __fadd_rn(r6, __fmul_rn(a[i + 6], a[i + 6]));
            r7 = __fadd_rn(r7, __fmul_rn(a[i + 7], a[i + 7]));
        }
        halves[h] = __fadd_rn(__fadd_rn(__fadd_rn(r0, r1), __fadd_rn(r2, r3)),
                              __fadd_rn(__fadd_rn(r4, r5), __fadd_rn(r6, r7)));
    }
    esq_g[k] = __fadd_rn(halves[0], halves[1]);
}

// ================= w split to bf16 hi (wl kept for layout compat, unused) =====
__global__ void vq_wsplit(const float* __restrict__ w, unsigned short* __restrict__ wh,
                          unsigned short* __restrict__ wl, int* __restrict__ cnt)
{
    if (blockIdx.x == 0 && threadIdx.x == 0) *cnt = 0;
    int i4 = (blockIdx.x * TPB + threadIdx.x) * 4;
    float4 v = *(const float4*)(w + i4);
    ushort4 hv = {bf16rn(v.x), bf16rn(v.y), bf16rn(v.z), bf16rn(v.w)};
    *(ushort4*)(wh + i4) = hv;
    (void)wl;
}

// ================= x transpose + bf16 hi only =================
__global__ void __launch_bounds__(TPB, 2)
vq_xsplit(const float* __restrict__ x, unsigned short* __restrict__ xh,
          unsigned short* __restrict__ xl)
{
    __shared__ float xs[CD][64];
    const int tid = threadIdx.x;
    const int b   = blockIdx.x >> 6;
    const int p0  = (blockIdx.x & 63) << 6;
    const float* xb = x + (size_t)b * CD * NP;
    const int g0 = b * NP + p0;

    #pragma unroll
    for (int r = 0; r < 16; ++r) {
        int f  = tid + r * TPB;
        int c  = f >> 4;
        int pq = (f & 15) << 2;
        float4 v = *(const float4*)(xb + (size_t)c * NP + p0 + pq);
        *(float4*)&xs[c][pq] = v;
    }
    __syncthreads();

    const int row = tid >> 2;
    #pragma unroll
    for (int s = 0; s < 8; ++s) {
        int slot = (tid & 3) + s * 4;
        int cb = slot * 8;
        float v0 = xs[cb + 0][row], v1 = xs[cb + 1][row], v2 = xs[cb + 2][row], v3 = xs[cb + 3][row];
        float v4 = xs[cb + 4][row], v5 = xs[cb + 5][row], v6 = xs[cb + 6][row], v7 = xs[cb + 7][row];
        unsigned short h0 = bf16rn(v0), h1 = bf16rn(v1), h2 = bf16rn(v2), h3 = bf16rn(v3);
        unsigned short h4 = bf16rn(v4), h5 = bf16rn(v5), h6 = bf16rn(v6), h7 = bf16rn(v7);
        int4 vh;
        vh.x = (int)h0 | ((int)h1 << 16);
        vh.y = (int)h2 | ((int)h3 << 16);
        vh.z = (int)h4 | ((int)h5 << 16);
        vh.w = (int)h6 | ((int)h7 << 16);
        size_t o = (size_t)(g0 + row) * CD + cb;
        *(int4*)(xh + o) = vh;
    }
    (void)xl;
}

// ================= MFMA GEMM + per-tile best/2nd (K=256, 4 chunks) =======
// Error audit: dropped split terms -> d2 error rms ~1.6e-3, max ~9e-3 over
// 6.7e7 pairs; a missed true-min implies approx-gap < 2*maxerr ~1.8e-2
// < EPS=0.04 -> always flagged -> exact rescore corrects. Margin > 2x.
// __launch_bounds__(256,3) is the proven sweet spot: (256,4)/no-bound -> VGPR
// cap 64 -> spill (R9/R16/R20); (256,3) -> 84 VGPR clean, 3 blocks/CU.
#define LEX_COMBINE(d1, i1, dv, od, oi, ov)                         \
    if ((od) < (d1) || ((od) == (d1) && (oi) < (i1))) {             \
        dv = fminf((d1), (ov)); d1 = (od); i1 = (oi);               \
    } else { dv = fminf((dv), (od)); }

#define VQ_LOAD(T, A0, A1, B0, B1, B2, B3, B4, B5, B6, B7)                    \
    {                                                                         \
        const int kcn_  = (T) < 3 ? (T) : 3;                                  \
        const int ke_   = kcn_ * 64;                                          \
        const unsigned short* sa_ = xh + (size_t)(g0 + rB) * CD + ke_ + sB * 8; \
        A0 = *(const int4*)(sa_);                                             \
        A1 = *(const int4*)(sa_ + 32 * CD);                                   \
        const unsigned short* sb_ = wh + (size_t)(n0 + rB) * CD + ke_ + sB * 8; \
        B0 = *(const int4*)(sb_ + 0 * 32 * CD);                               \
        B1 = *(const int4*)(sb_ + 1 * 32 * CD);                               \
        B2 = *(const int4*)(sb_ + 2 * 32 * CD);                               \
        B3 = *(const int4*)(sb_ + 3 * 32 * CD);                               \
        B4 = *(const int4*)(sb_ + 4 * 32 * CD);                               \
        B5 = *(const int4*)(sb_ + 5 * 32 * CD);                               \
        B6 = *(const int4*)(sb_ + 6 * 32 * CD);                               \
        B7 = *(const int4*)(sb_ + 7 * 32 * CD);                               \
    }

#define VQ_WRITE(A0, A1, B0, B1, B2, B3, B4, B5, B6, B7)                      \
    {                                                                         \
        unsigned short* aa_ = smem + rB * 64 + swz;                           \
        *(int4*)(aa_)            = A0;                                        \
        *(int4*)(aa_ + 32 * 64)  = A1;                                        \
        unsigned short* bb_ = smem + 4096 + rB * 64 + swz;                    \
        *(int4*)(bb_ + 0 * 2048) = B0; *(int4*)(bb_ + 1 * 2048) = B1;         \
        *(int4*)(bb_ + 2 * 2048) = B2; *(int4*)(bb_ + 3 * 2048) = B3;         \
        *(int4*)(bb_ + 4 * 2048) = B4; *(int4*)(bb_ + 5 * 2048) = B5;         \
        *(int4*)(bb_ + 6 * 2048) = B6; *(int4*)(bb_ + 7 * 2048) = B7;         \
    }

#define VQ_COMP()                                                                         \
    {                                                                                     \
        const unsigned short* Ab = smem;                                                  \
        const unsigned short* Bb = smem + 4096;                                           \
        for (int kk = 0; kk < 2; ++kk) {                                                  \
            const int s8 = ((hi2 + kk * 4) ^ rxor) * 8;                                   \
            v8s af0 = *(const v8s*)(Ab + (0 * 16 + lo4) * 64 + s8);                       \
            v8s af1 = *(const v8s*)(Ab + (1 * 16 + lo4) * 64 + s8);                       \
            v8s af2 = *(const v8s*)(Ab + (2 * 16 + lo4) * 64 + s8);                       \
            v8s af3 = *(const v8s*)(Ab + (3 * 16 + lo4) * 64 + s8);                       \
            v8s bf0 = *(const v8s*)(Bb + (wv * 64 + 0 * 16 + lo4) * 64 + s8);             \
            v8s bf1 = *(const v8s*)(Bb + (wv * 64 + 1 * 16 + lo4) * 64 + s8);             \
            v8s bf2 = *(const v8s*)(Bb + (wv * 64 + 2 * 16 + lo4) * 64 + s8);             \
            v8s bf3 = *(const v8s*)(Bb + (wv * 64 + 3 * 16 + lo4) * 64 + s8);             \
            acc[0][0] = __builtin_amdgcn_mfma_f32_16x16x32_bf16(af0, bf0, acc[0][0], 0, 0, 0); \
            acc[0][1] = __builtin_amdgcn_mfma_f32_16x16x32_bf16(af0, bf1, acc[0][1], 0, 0, 0); \
            acc[0][2] = __builtin_amdgcn_mfma_f32_16x16x32_bf16(af0, bf2, acc[0][2], 0, 0, 0); \
            acc[0][3] = __builtin_amdgcn_mfma_f32_16x16x32_bf16(af0, bf3, acc[0][3], 0, 0, 0); \
            acc[1][0] = __builtin_amdgcn_mfma_f32_16x16x32_bf16(af1, bf0, acc[1][0], 0, 0, 0); \
            acc[1][1] = __builtin_amdgcn_mfma_f32_16x16x32_bf16(af1, bf1, acc[1][1], 0, 0, 0); \
            acc[1][2] = __builtin_amdgcn_mfma_f32_16x16x32_bf16(af1, bf2, acc[1][2], 0, 0, 0); \
            acc[1][3] = __builtin_amdgcn_mfma_f32_16x16x32_bf16(af1, bf3, acc[1][3], 0, 0, 0); \
            acc[2][0] = __builtin_amdgcn_mfma_f32_16x16x32_bf16(af2, bf0, acc[2][0], 0, 0, 0); \
            acc[2][1] = __builtin_amdgcn_mfma_f32_16x16x32_bf16(af2, bf1, acc[2][1], 0, 0, 0); \
            acc[2][2] = __builtin_amdgcn_mfma_f32_16x16x32_bf16(af2, bf2, acc[2][2], 0, 0, 0); \
            acc[2][3] = __builtin_amdgcn_mfma_f32_16x16x32_bf16(af2, bf3, acc[2][3], 0, 0, 0); \
            acc[3][0] = __builtin_amdgcn_mfma_f32_16x16x32_bf16(af3, bf0, acc[3][0], 0, 0, 0); \
            acc[3][1] = __builtin_amdgcn_mfma_f32_16x16x32_bf16(af3, bf1, acc[3][1], 0, 0, 0); \
            acc[3][2] = __builtin_amdgcn_mfma_f32_16x16x32_bf16(af3, bf2, acc[3][2], 0, 0, 0); \
            acc[3][3] = __builtin_amdgcn_mfma_f32_16x16x32_bf16(af3, bf3, acc[3][3], 0, 0, 0); \
        }                                                                                 \
    }

__global__ void __launch_bounds__(TPB, 3)
vq_mfma(const unsigned short* __restrict__ xh, const unsigned short* __restrict__ xl,
        const unsigned short* __restrict__ wh, const unsigned short* __restrict__ wl,
        const float* __restrict__ esq, float4* __restrict__ redg)
{
    __shared__ unsigned short smem[20480];          // 40 KB: As 8KB | Bs 32KB

    const int tid = threadIdx.x;
    const int mt  = blockIdx.x >> 2;
    const int nt  = blockIdx.x & 3;
    const int g0  = mt * 64;
    const int n0  = nt * 256;

    const int wv  = tid >> 6;
    const int l   = tid & 63;
    const int lo4 = l & 15;
    const int hi2 = l >> 4;
    const int rxor = lo4 & 7;

    const int rB  = tid >> 3;
    const int sB  = tid & 7;
    const int swz = ((sB ^ (rB & 7)) * 8);

    v4f acc[4][4];
    #pragma unroll
    for (int i = 0; i < 4; ++i)
        #pragma unroll
        for (int j = 0; j < 4; ++j) acc[i][j] = (v4f)0.f;

    int4 pa0, pa1, pb0, pb1, pb2, pb3, pb4, pb5, pb6, pb7;

    VQ_LOAD(0, pa0, pa1, pb0, pb1, pb2, pb3, pb4, pb5, pb6, pb7)
    VQ_WRITE(pa0, pa1, pb0, pb1, pb2, pb3, pb4, pb5, pb6, pb7)
    VQ_LOAD(1, pa0, pa1, pb0, pb1, pb2, pb3, pb4, pb5, pb6, pb7)
    __syncthreads();

    for (int kc = 0; kc < 4; ++kc) {                // K = 256: 4 chunks
        VQ_COMP()
        __syncthreads();
        VQ_WRITE(pa0, pa1, pb0, pb1, pb2, pb3, pb4, pb5, pb6, pb7)
        VQ_LOAD(kc + 2, pa0, pa1, pb0, pb1, pb2, pb3, pb4, pb5, pb6, pb7)
        __syncthreads();
    }

    const float eq0 = esq[n0 + wv * 64 + 0 * 16 + lo4];
    const float eq1 = esq[n0 + wv * 64 + 1 * 16 + lo4];
    const float eq2 = esq[n0 + wv * 64 + 2 * 16 + lo4];
    const float eq3 = esq[n0 + wv * 64 + 3 * 16 + lo4];
    const int nbase = n0 + wv * 64;

    float4* red4 = (float4*)smem;

    #pragma unroll
    for (int i = 0; i < 4; ++i) {
        float d1[4], dv[4]; int ix[4];
        #pragma unroll
        for (int r = 0; r < 4; ++r) {
            float s = fmaf(-2.f, acc[i][0][r], eq0);
            d1[r] = s; ix[r] = nbase + lo4; dv[r] = FLT_MAX;
        }
        #pragma unroll
        for (int r = 0; r < 4; ++r) {
            float s1 = fmaf(-2.f, acc[i][1][r], eq1);
            if (s1 < d1[r]) { dv[r] = d1[r]; d1[r] = s1; ix[r] = nbase + 16 + lo4; }
            else dv[r] = fminf(dv[r], s1);
            float s2 = fmaf(-2.f, acc[i][2][r], eq2);
            if (s2 < d1[r]) { dv[r] = d1[r]; d1[r] = s2; ix[r] = nbase + 32 + lo4; }
            else dv[r] = fminf(dv[r], s2);
            float s3 = fmaf(-2.f, acc[i][3][r], eq3);
            if (s3 < d1[r]) { dv[r] = d1[r]; d1[r] = s3; ix[r] = nbase + 48 + lo4; }
            else dv[r] = fminf(dv[r], s3);
        }
        #pragma unroll
        for (int m = 1; m <= 8; m <<= 1) {
            #pragma unroll
            for (int r = 0; r < 4; ++r) {
                float od = __shfl_xor(d1[r], m);
                int   oi = __shfl_xor(ix[r], m);
                float ov = __shfl_xor(dv[r], m);
                LEX_COMBINE(d1[r], ix[r], dv[r], od, oi, ov)
            }
        }
        if (lo4 == 0) {
            #pragma unroll
            for (int r = 0; r < 4; ++r) {
                float4 e; e.x = d1[r]; e.y = dv[r]; e.z = __int_as_float(ix[r]); e.w = 0.f;
                red4[wv * 64 + i * 16 + hi2 * 4 + r] = e;
            }
        }
    }
    __syncthreads();

    if (tid < 64) {
        float4 a = red4[tid];
        #pragma unroll
        for (int w2 = 1; w2 < 4; ++w2) {
            float4 c = red4[w2 * 64 + tid];
            float od = c.x; int oi = __float_as_int(c.z); float ov = c.y;
            float d1 = a.x; int i1 = __float_as_int(a.z); float dv = a.y;
            LEX_COMBINE(d1, i1, dv, od, oi, ov)
            a.x = d1; a.y = dv; a.z = __int_as_float(i1);
        }
        redg[(size_t)(g0 + tid) * 4 + nt] = a;
    }
}

// ================= combine 4 n-tiles, write codes, flag near-ties =================
__global__ void vq_finalize(const float4* __restrict__ redg, float* __restrict__ out,
                            int* __restrict__ codes, int* __restrict__ cnt,
                            int* __restrict__ list)
{
    int g = blockIdx.x * TPB + threadIdx.x;
    float4 a = redg[(size_t)g * 4 + 0];
    float d1 = a.x; int i1 = __float_as_int(a.z); float dv = a.y;
    #pragma unroll
    for (int t = 1; t < 4; ++t) {
        float4 c = redg[(size_t)g * 4 + t];
        float od = c.x; int oi = __float_as_int(c.z); float ov = c.y;
        LEX_COMBINE(d1, i1, dv, od, oi, ov)
    }
    out[g] = (float)i1;
    codes[g] = i1;
    if (dv - d1 < EPS) {
        int pos = atomicAdd(cnt, 1);
        list[pos] = g;
    }
}

// ================= w transpose (fp32) for coalesced rescore =================
__global__ void vq_wT(const float* __restrict__ w, float* __restrict__ wT)
{
    __shared__ float tile[32][33];
    const int tid = threadIdx.x;
    const int r0 = blockIdx.x * 32;
    const int cc = tid & 31;
    const int rr0 = (tid >> 5) * 4;
    for (int ct = 0; ct < 8; ++ct) {
        __syncthreads();
        #pragma unroll
        for (int k = 0; k < 4; ++k)
            tile[rr0 + k][cc] = w[(size_t)(r0 + rr0 + k) * CD + ct * 32 + cc];
        __syncthreads();
        #pragma unroll
        for (int k = 0; k < 4; ++k)
            wT[(size_t)(ct * 32 + rr0 + k) * KC + r0 + cc] = tile[cc][rr0 + k];
    }
}

// ================= exact rescore, coalesced + amortized (8 points/block) =================
#define RACC(pp) float a##pp##0 = 0.f, a##pp##1 = 0.f, a##pp##2 = 0.f, a##pp##3 = 0.f;
#define RFMA(pp)                                          \
    {                                                     \
        float xv = xrow[pp][c];                           \
        a##pp##0 = fmaf(xv, w0v, a##pp##0);               \
        a##pp##1 = fmaf(xv, w1v, a##pp##1);               \
        a##pp##2 = fmaf(xv, w2v, a##pp##2);               \
        a##pp##3 = fmaf(xv, w3v, a##pp##3);               \
    }
#define REPI(pp)                                                                     \
    if (pp < m) {                                                                    \
        float xq = xqs[pp];                                                          \
        float bd; int bi;                                                            \
        float d2 = __fadd_rn(__fsub_rn(xq, __fmul_rn(2.0f, a##pp##0)), e0);          \
        bd = d2; bi = tid;                                                           \
        d2 = __fadd_rn(__fsub_rn(xq, __fmul_rn(2.0f, a##pp##1)), e1);                \
        if (d2 < bd) { bd = d2; bi = tid + 256; }                                    \
        d2 = __fadd_rn(__fsub_rn(xq, __fmul_rn(2.0f, a##pp##2)), e2);                \
        if (d2 < bd) { bd = d2; bi = tid + 512; }                                    \
        d2 = __fadd_rn(__fsub_rn(xq, __fmul_rn(2.0f, a##pp##3)), e3);                \
        if (d2 < bd) { bd = d2; bi = tid + 768; }                                    \
        sd[pp][tid] = bd; si[pp][tid] = bi;                                          \
    }

__global__ void vq_rescore(const float* __restrict__ x, const float* __restrict__ wT,
                           const float* __restrict__ esq, const int* __restrict__ cnt,
                           const int* __restrict__ list, float* __restrict__ out,
                           int* __restrict__ codes)
{
    __shared__ float xrow[8][CD];
    __shared__ float xqs[8];
    __shared__ float sd[8][TPB];
    __shared__ int   si[8][TPB];
    const int tid = threadIdx.x;
    const int n = *cnt;

    for (int base = blockIdx.x * 8; base < n; base += gridDim.x * 8) {
        const int m = (n - base < 8) ? (n - base) : 8;
        __syncthreads();
        #pragma unroll
        for (int pp = 0; pp < 8; ++pp) {
            if (pp < m) {
                const int g = list[base + pp];
                const int b = g >> 12, p = g & 4095;
                xrow[pp][tid] = x[(size_t)b * CD * NP + (size_t)tid * NP + p];
            } else {
                xrow[pp][tid] = 0.f;
            }
        }
        __syncthreads();
        if (tid < m) {
            const int pp = tid;
            float halves[2];
            #pragma unroll
            for (int h = 0; h < 2; ++h) {
                const float* a = &xrow[pp][h * 128];
                float r0 = __fmul_rn(a[0], a[0]);
                float r1 = __fmul_rn(a[1], a[1]);
                float r2 = __fmul_rn(a[2], a[2]);
                float r3 = __fmul_rn(a[3], a[3]);
                float r4 = __fmul_rn(a[4], a[4]);
                float r5 = __fmul_rn(a[5], a[5]);
                float r6 = __fmul_rn(a[6], a[6]);
                float r7 = __fmul_rn(a[7], a[7]);
                for (int i = 8; i < 128; i += 8) {
                    r0 = __fadd_rn(r0, __fmul_rn(a[i + 0], a[i + 0]));
                    r1 = __fadd_rn(r1, __fmul_rn(a[i + 1], a[i + 1]));
                    r2 = __fadd_rn(r2, __fmul_rn(a[i + 2], a[i + 2]));
                    r3 = __fadd_rn(r3, __fmul_rn(a[i + 3], a[i + 3]));
                    r4 = __fadd_rn(r4, __fmul_rn(a[i + 4], a[i + 4]));
                    r5 = __fadd_rn(r5, __fmul_rn(a[i + 5], a[i + 5]));
                    r6 = __fadd_rn(r6, __fmul_rn(a[i + 6], a[i + 6]));
                    r7 = __fadd_rn(r7, __fmul_rn(a[i + 7], a[i + 7]));
                }
                halves[h] = __fadd_rn(__fadd_rn(__fadd_rn(r0, r1), __fadd_rn(r2, r3)),
                                      __fadd_rn(__fadd_rn(r4, r5), __fadd_rn(r6, r7)));
            }
            xqs[pp] = __fadd_rn(halves[0], halves[1]);
        }
        __syncthreads();

        RACC(0) RACC(1) RACC(2) RACC(3) RACC(4) RACC(5) RACC(6) RACC(7)
        #pragma unroll 4
        for (int c = 0; c < CD; ++c) {
            const float* wTc = wT + ((size_t)c << 10);
            float w0v = wTc[tid];
            float w1v = wTc[tid + 256];
            float w2v = wTc[tid + 512];
            float w3v = wTc[tid + 768];
            RFMA(0) RFMA(1) RFMA(2) RFMA(3) RFMA(4) RFMA(5) RFMA(6) RFMA(7)
        }

        const float e0 = esq[tid];
        const float e1 = esq[tid + 256];
        const float e2 = esq[tid + 512];
        const float e3 = esq[tid + 768];
        REPI(0) REPI(1) REPI(2) REPI(3) REPI(4) REPI(5) REPI(6) REPI(7)
        __syncthreads();

        if (tid < m) {
            const int pp = tid;
            float d1 = sd[pp][0]; int i1 = si[pp][0];
            for (int t = 1; t < TPB; ++t) {
                float od = sd[pp][t]; int oi = si[pp][t];
                if (od < d1 || (od == d1 && oi < i1)) { d1 = od; i1 = oi; }
            }
            const int g = list[base + pp];
            codes[g] = i1;
            out[g] = (float)i1;
        }
    }
}

// ================= gather x_new (LDS-staged, coalesced w reads) =================
__global__ void __launch_bounds__(TPB, 2)
vq_gather(const float* __restrict__ w, const int* __restrict__ codes,
          float* __restrict__ outx)
{
    __shared__ float lw[64][257];
    __shared__ int   lc[64];
    const int tid = threadIdx.x;
    const int b   = blockIdx.x >> 6;
    const int p0  = (blockIdx.x & 63) << 6;

    if (tid < 64) lc[tid] = codes[b * NP + p0 + tid];
    __syncthreads();

    #pragma unroll 8
    for (int pp = 0; pp < 64; ++pp) {
        lw[pp][tid] = w[(size_t)lc[pp] * CD + tid];
    }
    __syncthreads();

    const int p  = tid & 63;
    const int cg = tid >> 6;
    size_t obase = (size_t)b * CD * NP + (size_t)p0 + p;
    #pragma unroll 8
    for (int r = 0; r < 64; ++r) {
        int c = (cg << 6) + r;
        outx[obase + (size_t)c * NP] = lw[p][c];
    }
}

// ================= R3 fallback (proven exact fp32 path, needs only 4 KB ws) =================
#define FMA_ROW(i, xc)                              \
    acc##i##0 = fmaf((xc), wv0.x, acc##i##0);       \
    acc##i##1 = fmaf((xc), wv0.y, acc##i##1);       \
    acc##i##2 = fmaf((xc), wv0.z, acc##i##2);       \
    acc##i##3 = fmaf((xc), wv0.w, acc##i##3);       \
    acc##i##4 = fmaf((xc), wv1.x, acc##i##4);       \
    acc##i##5 = fmaf((xc), wv1.y, acc##i##5);       \
    acc##i##6 = fmaf((xc), wv1.z, acc##i##6);       \
    acc##i##7 = fmaf((xc), wv1.w, acc##i##7);
#define D2_ONE(i, j, ev)                                                          \
    {                                                                             \
        float d2 = __fadd_rn(__fsub_rn(xq[i], __fmul_rn(2.0f, acc##i##j)), (ev)); \
        if (d2 < bestd[i]) { bestd[i] = d2; besti[i] = fn0 + jl + j; }            \
    }
#define D2_ROW(i)                                                                 \
    D2_ONE(i, 0, e0.x) D2_ONE(i, 1, e0.y) D2_ONE(i, 2, e0.z) D2_ONE(i, 3, e0.w)  \
    D2_ONE(i, 4, e1.x) D2_ONE(i, 5, e1.y) D2_ONE(i, 6, e1.z) D2_ONE(i, 7, e1.w)
#define DECL_ACC(i) \
    float acc##i##0 = 0.f, acc##i##1 = 0.f, acc##i##2 = 0.f, acc##i##3 = 0.f, \
          acc##i##4 = 0.f, acc##i##5 = 0.f, acc##i##6 = 0.f, acc##i##7 = 0.f;

__global__ void __launch_bounds__(TPB, 2)
vq_fused(const float* __restrict__ x, const float* __restrict__ w,
         const float* __restrict__ esq_g, float* __restrict__ out)
{
    __shared__ float xs[CD][64];
    __shared__ float ws[2][16][128];
    const int tid = threadIdx.x;
    const int blk = blockIdx.x;
    const int b   = blk >> 6;
    const int p0  = (blk & 63) << 6;
    const float* xb = x + (size_t)b * CD * NP;
    #pragma unroll
    for (int r = 0; r < 16; ++r) {
        int f  = tid + r * TPB;
        int c  = f >> 4;
        int pq = (f & 15) << 2;
        float4 v = *(const float4*)(xb + (size_t)c * NP + p0 + pq);
        *(float4*)&xs[c][pq] = v;
    }
    __syncthreads();
    const int sj = tid & 63;
    const int sc = (tid >> 6) << 2;
    const float* wbase = w + (size_t)sj * CD + sc;
    float* xsq_tmp = &ws[1][0][0];
    if (tid < 64) {
        float halves[2];
        #pragma unroll
        for (int h = 0; h < 2; ++h) {
            int cb = h * 128;
            float r0 = __fmul_rn(xs[cb + 0][tid], xs[cb + 0][tid]);
            float r1 = __fmul_rn(xs[cb + 1][tid], xs[cb + 1][tid]);
            float r2 = __fmul_rn(xs[cb + 2][tid], xs[cb + 2][tid]);
            float r3 = __fmul_rn(xs[cb + 3][tid], xs[cb + 3][tid]);
            float r4 = __fmul_rn(xs[cb + 4][tid], xs[cb + 4][tid]);
            float r5 = __fmul_rn(xs[cb + 5][tid], xs[cb + 5][tid]);
            float r6 = __fmul_rn(xs[cb + 6][tid], xs[cb + 6][tid]);
            float r7 = __fmul_rn(xs[cb + 7][tid], xs[cb + 7][tid]);
            for (int i = 8; i < 128; i += 8) {
                r0 = __fadd_rn(r0, __fmul_rn(xs[cb + i + 0][tid], xs[cb + i + 0][tid]));
                r1 = __fadd_rn(r1, __fmul_rn(xs[cb + i + 1][tid], xs[cb + i + 1][tid]));
                r2 = __fadd_rn(r2, __fmul_rn(xs[cb + i + 2][tid], xs[cb + i + 2][tid]));
                r3 = __fadd_rn(r3, __fmul_rn(xs[cb + i + 3][tid], xs[cb + i + 3][tid]));
                r4 = __fadd_rn(r4, __fmul_rn(xs[cb + i + 4][tid], xs[cb + i + 4][tid]));
                r5 = __fadd_rn(r5, __fmul_rn(xs[cb + i + 5][tid], xs[cb + i + 5][tid]));
                r6 = __fadd_rn(r6, __fmul_rn(xs[cb + i + 6][tid], xs[cb + i + 6][tid]));
                r7 = __fadd_rn(r7, __fmul_rn(xs[cb + i + 7][tid], xs[cb + i + 7][tid]));
            }
            halves[h] = __fadd_rn(__fadd_rn(__fadd_rn(r0, r1), __fadd_rn(r2, r3)),
                                  __fadd_rn(__fadd_rn(r4, r5), __fadd_rn(r6, r7)));
        }
        xsq_tmp[tid] = __fadd_rn(halves[0], halves[1]);
    }
    {
        #pragma unroll
        for (int r = 0; r < 2; ++r) {
            int j = sj + (r << 6);
            float4 v = *(const float4*)(w + (size_t)j * CD + sc);
            ws[0][sc + 0][j] = v.x; ws[0][sc + 1][j] = v.y;
            ws[0][sc + 2][j] = v.z; ws[0][sc + 3][j] = v.w;
        }
    }
    __syncthreads();
    const int pl = (tid & 15) << 2;
    const int jl = (tid >> 4) << 3;
    float xq[4] = { xsq_tmp[pl], xsq_tmp[pl + 1], xsq_tmp[pl + 2], xsq_tmp[pl + 3] };
    __syncthreads();
    float bestd[4] = {FLT_MAX, FLT_MAX, FLT_MAX, FLT_MAX};
    int   besti[4] = {0, 0, 0, 0};
    for (int tile = 0; tile < 8; ++tile) {
        const int fn0 = tile * 128;
        float4 e0 = *(const float4*)(esq_g + fn0 + jl);
        float4 e1 = *(const float4*)(esq_g + fn0 + jl + 4);
        DECL_ACC(0) DECL_ACC(1) DECL_ACC(2) DECL_ACC(3)
        for (int ch = 0; ch < 16; ++ch) {
            const int t   = tile * 16 + ch;
            const int cur = t & 1;
            const int tn  = (t + 1) & 127;
            const size_t poff = (size_t)((tn >> 4) << 7) * CD + ((tn & 15) << 4);
            float4 pa = *(const float4*)(wbase + poff);
            float4 pb = *(const float4*)(wbase + poff + (size_t)64 * CD);
            const int c0 = ch * 16;
            #pragma unroll
            for (int c = 0; c < 16; ++c) {
                float4 xv  = *(const float4*)&xs[c0 + c][pl];
                float4 wv0 = *(const float4*)&ws[cur][c][jl];
                float4 wv1 = *(const float4*)&ws[cur][c][jl + 4];
                FMA_ROW(0, xv.x)
                FMA_ROW(1, xv.y)
                FMA_ROW(2, xv.z)
                FMA_ROW(3, xv.w)
            }
            {
                const int nb = cur ^ 1;
                ws[nb][sc + 0][sj]      = pa.x; ws[nb][sc + 1][sj]      = pa.y;
                ws[nb][sc + 2][sj]      = pa.z; ws[nb][sc + 3][sj]      = pa.w;
                ws[nb][sc + 0][sj + 64] = pb.x; ws[nb][sc + 1][sj + 64] = pb.y;
                ws[nb][sc + 2][sj + 64] = pb.z; ws[nb][sc + 3][sj + 64] = pb.w;
            }
            __syncthreads();
        }
        D2_ROW(0) D2_ROW(1) D2_ROW(2) D2_ROW(3)
    }
    __syncthreads();
    float* redd  = &ws[0][0][0];
    int*   redi  = (int*)(redd + 1024);
    int*   codes = (int*)&ws[1][0][0];
    {
        int g = tid >> 4;
        #pragma unroll
        for (int i = 0; i < 4; ++i) {
            redd[(pl + i) * 16 + g] = bestd[i];
            redi[(pl + i) * 16 + g] = besti[i];
        }
    }
    __syncthreads();
    if (tid < 64) {
        float bd = FLT_MAX; int bi = 0x7fffffff;
        #pragma unroll
        for (int g = 0; g < 16; ++g) {
            float d = redd[tid * 16 + g];
            int   i = redi[tid * 16 + g];
            if (d < bd || (d == bd && i < bi)) { bd = d; bi = i; }
        }
        codes[tid] = bi;
        out[(size_t)b * NP + p0 + tid] = (float)bi;
    }
    __syncthreads();
    {
        float* outx = out + (size_t)B_SZ * NP;
        int p  = tid & 63;
        int cg = tid >> 6;
        const float* wr = w + (size_t)codes[p] * CD;
        size_t obase = (size_t)b * CD * NP + (size_t)p0 + p;
        #pragma unroll 4
        for (int r = 0; r < 64; ++r) {
            int c = (cg << 6) + r;
            outx[obase + (size_t)c * NP] = wr[c];
        }
    }
}

extern "C" void kernel_launch(void* const* d_in, const int* in_sizes, int n_in,
                              void* d_out, int out_size, void* d_ws, size_t ws_size,
                              hipStream_t stream)
{
    const float* x = (const float*)d_in[0];     // [16,256,64,64]
    const float* w = (const float*)d_in[1];     // [1024,256]
    float* out    = (float*)d_out;              // 65536 code + 16777216 x_new
    char*  ws     = (char*)d_ws;

    float* esq = (float*)(ws + OFF_ESQ);
    hipLaunchKernelGGL(vq_esq, dim3(4), dim3(TPB), 0, stream, w, esq);

    if (ws_size < (size_t)WS_NEED) {
        hipLaunchKernelGGL(vq_fused, dim3(1024), dim3(TPB), 0, stream, x, w, esq, out);
        return;
    }

    int*   cnt   = (int*)(ws + OFF_CNT);
    int*   codes = (int*)(ws + OFF_CODE);
    int*   list  = (int*)(ws + OFF_LIST);
    float4* redg = (float4*)(ws + OFF_RED);
    float*  wT   = (float*)(ws + OFF_WT);
    unsigned short* wh = (unsigned short*)(ws + OFF_WH);
    unsigned short* wl = (unsigned short*)(ws + OFF_WL);
    unsigned short* xh = (unsigned short*)(ws + OFF_XH);
    unsigned short* xl = (unsigned short*)(ws + OFF_XL);

    hipLaunchKernelGGL(vq_wsplit,   dim3(256),  dim3(TPB), 0, stream, w, wh, wl, cnt);
    hipLaunchKernelGGL(vq_xsplit,   dim3(1024), dim3(TPB), 0, stream, x, xh, xl);
    hipLaunchKernelGGL(vq_mfma,     dim3(4096), dim3(TPB), 0, stream, xh, xl, wh, wl, esq, redg);
    hipLaunchKernelGGL(vq_finalize, dim3(256),  dim3(TPB), 0, stream, redg, out, codes, cnt, list);
    hipLaunchKernelGGL(vq_wT,       dim3(32),   dim3(TPB), 0, stream, w, wT);
    hipLaunchKernelGGL(vq_rescore,  dim3(1024), dim3(TPB), 0, stream, x, wT, esq, cnt, list, out, codes);
    hipLaunchKernelGGL(vq_gather,   dim3(1024), dim3(TPB), 0, stream, w, codes, out + (size_t)B_SZ * NP);
}